// Round 3
// baseline (597.331 us; speedup 1.0000x reference)
//
#include <hip/hip_runtime.h>
#include <hip/hip_bf16.h>
#include <math.h>

#define S_IN   22
#define S_DIM  256
#define PE_D   64
#define L_TOT  1024
// region starts (cumsum of [1,400,300,15,110,50,100,48])
// 0:[0,1) collapse, 1:hd[1,401), 2:mhc[401,701), 3:pep[701,716),
// 4:lv[716,826), 5:lj[826,876), 6:hv[876,976), 7:hj[976,1024)

__device__ __forceinline__ int region_of(int p) {
    return (p >= 1) + (p >= 401) + (p >= 701) + (p >= 716) +
           (p >= 826) + (p >= 876) + (p >= 976);
}

__global__ __launch_bounds__(256) void s_out_kernel(
    const float* __restrict__ hd,  const int* __restrict__ hd_idx,
    const float* __restrict__ mhc, const int* __restrict__ mhc_idx,
    const float* __restrict__ pep, const int* __restrict__ pep_idx,
    const float* __restrict__ lv,  const int* __restrict__ lv_idx,
    const float* __restrict__ lj,  const int* __restrict__ lj_idx,
    const float* __restrict__ hv,  const int* __restrict__ hv_idx,
    const float* __restrict__ hj,  const int* __restrict__ hj_idx,
    const int*  __restrict__ mask,
    const float* __restrict__ W_seq, const float* __restrict__ b_seq,
    const float* __restrict__ W_pos, const float* __restrict__ b_pos,
    const float* __restrict__ collapse_token,
    const float* __restrict__ collapse_weight,
    const float* __restrict__ rw_hd, const float* __restrict__ rw_mhc,
    const float* __restrict__ rw_pep, const float* __restrict__ rw_lv,
    const float* __restrict__ rw_lj, const float* __restrict__ rw_hv,
    const float* __restrict__ rw_hj,
    float* __restrict__ out)
{
    const int row = blockIdx.x;
    const int c   = threadIdx.x;   // 0..255, one output column each

    if (row == 0) {
        out[c] = collapse_weight[0] * collapse_token[c];
        return;
    }

    // block-uniform region select
    const float* aa; const int* idx; const float* rw; int start; int isHd = 0;
    if      (row < 401) { aa = hd;  idx = hd_idx;  rw = rw_hd;  start = 1;   isHd = 1; }
    else if (row < 701) { aa = mhc; idx = mhc_idx; rw = rw_mhc; start = 401; }
    else if (row < 716) { aa = pep; idx = pep_idx; rw = rw_pep; start = 701; }
    else if (row < 826) { aa = lv;  idx = lv_idx;  rw = rw_lv;  start = 716; }
    else if (row < 876) { aa = lj;  idx = lj_idx;  rw = rw_lj;  start = 826; }
    else if (row < 976) { aa = hv;  idx = hv_idx;  rw = rw_hv;  start = 876; }
    else                { aa = hj;  idx = hj_idx;  rw = rw_hj;  start = 976; }
    const int r = row - start;

    __shared__ float sa[S_IN];
    __shared__ float pe[PE_D];

    if (c < S_IN) {
        float v = aa[r * S_IN + c];
        if (isHd && mask[r] == 1) v = 0.0f;
        sa[c] = v;
    }
    if (c >= 64 && c < 64 + PE_D) {
        const int d = c - 64;
        const float p = (float)idx[r];
        // 10000^(-d/64) = exp(-(d/64)*ln(10000))
        const float inv_freq = expf(-((float)d / (float)PE_D) * 9.210340371976184f);
        const float ang = p * inv_freq;
        pe[d] = (d & 1) ? cosf(ang) : sinf(ang);
    }
    __syncthreads();

    float acc_s = b_seq[c];
    #pragma unroll
    for (int f = 0; f < S_IN; ++f)
        acc_s = fmaf(sa[f], W_seq[f * S_DIM + c], acc_s);

    float acc_p = b_pos[c];
    #pragma unroll
    for (int d = 0; d < PE_D; ++d)
        acc_p = fmaf(pe[d], W_pos[d * S_DIM + c], acc_p);

    out[row * S_DIM + c] = rw[0] * acc_s + rw[1] * acc_p;
}

// z: (1024,1024,128) fp32. Only 26 distinct pid values -> 26 distinct rows.
// Precompute 26x128 fp32 table in LDS; each thread emits one 16B (float4) chunk.
__global__ __launch_bounds__(256) void z_kernel(
    const float* __restrict__ W_p1, const float* __restrict__ b_p1,
    const float* __restrict__ W_p2, const float* __restrict__ b_p2,
    float4* __restrict__ z)
{
    __shared__ alignas(16) float table[26 * 128];
    for (int t = threadIdx.x; t < 26 * 128; t += 256) {
        const int p = t >> 7, k = t & 127;
        float v;
        if (k < 64) v = W_p1[(p >> 2) * 64 + k]       + b_p1[k];
        else        v = W_p2[(p & 3) * 64 + (k - 64)] + b_p2[k - 64];
        table[t] = v;
    }
    __syncthreads();

    const int total  = (L_TOT * L_TOT * 128) / 4;   // 33,554,432 float4 chunks
    const int stride = gridDim.x * blockDim.x;
    for (int cidx = blockIdx.x * blockDim.x + threadIdx.x; cidx < total; cidx += stride) {
        const int pair = cidx >> 5;          // 32 float4 chunks per (i,j) row
        const int i = pair >> 10;
        const int j = pair & 1023;
        const int ri = region_of(i);
        const int rj = region_of(j);
        int pid;
        if (ri == 0 || rj == 0) {
            pid = (ri + rj == 0) ? 0 : 1;               // collapse overrides
        } else if (ri == 1 && rj == 1) {                // hd-hd
            const int di = (i > j) ? (i - j) : (j - i);
            pid = (di == 1) ? 2 : ((di > 1) ? 3 : 0);
        } else if (ri == 1 || rj == 1) {                // hd vs cond
            pid = 4;
        } else if (ri == rj) {                          // same cond region
            pid = 3 + ri;
        } else {                                        // cross cond regions
            const int m1 = ((ri < rj) ? ri : rj) - 2;
            const int m2 = ((ri > rj) ? ri : rj) - 2;
            pid = 11 + m1 * 6 - (m1 * (m1 + 1)) / 2 + (m2 - m1 - 1);
        }
        const int koff = cidx & 31;          // float4 index within the 128-row
        const float4* src =
            reinterpret_cast<const float4*>(&table[(pid << 7) + (koff << 2)]);
        z[cidx] = *src;
    }
}

extern "C" void kernel_launch(void* const* d_in, const int* in_sizes, int n_in,
                              void* d_out, int out_size, void* d_ws, size_t ws_size,
                              hipStream_t stream) {
    const float* hd       = (const float*)d_in[0];
    const int*   hd_idx   = (const int*)  d_in[1];
    const float* mhc      = (const float*)d_in[2];
    const int*   mhc_idx  = (const int*)  d_in[3];
    const float* pep      = (const float*)d_in[4];
    const int*   pep_idx  = (const int*)  d_in[5];
    const float* lv       = (const float*)d_in[6];
    const int*   lv_idx   = (const int*)  d_in[7];
    const float* lj       = (const float*)d_in[8];
    const int*   lj_idx   = (const int*)  d_in[9];
    const float* hv       = (const float*)d_in[10];
    const int*   hv_idx   = (const int*)  d_in[11];
    const float* hj       = (const float*)d_in[12];
    const int*   hj_idx   = (const int*)  d_in[13];
    const int*   mask     = (const int*)  d_in[14];
    const float* W_seq    = (const float*)d_in[15];
    const float* b_seq    = (const float*)d_in[16];
    const float* W_pos    = (const float*)d_in[17];
    const float* b_pos    = (const float*)d_in[18];
    const float* W_p1     = (const float*)d_in[19];
    const float* b_p1     = (const float*)d_in[20];
    const float* W_p2     = (const float*)d_in[21];
    const float* b_p2     = (const float*)d_in[22];
    const float* collapse_token  = (const float*)d_in[23];
    const float* collapse_weight = (const float*)d_in[24];
    const float* rw_hd    = (const float*)d_in[25];
    const float* rw_mhc   = (const float*)d_in[26];
    const float* rw_pep   = (const float*)d_in[27];
    const float* rw_lv    = (const float*)d_in[28];
    const float* rw_lj    = (const float*)d_in[29];
    const float* rw_hv    = (const float*)d_in[30];
    const float* rw_hj    = (const float*)d_in[31];

    float* out = (float*)d_out;

    s_out_kernel<<<L_TOT, 256, 0, stream>>>(
        hd, hd_idx, mhc, mhc_idx, pep, pep_idx, lv, lv_idx, lj, lj_idx,
        hv, hv_idx, hj, hj_idx, mask, W_seq, b_seq, W_pos, b_pos,
        collapse_token, collapse_weight,
        rw_hd, rw_mhc, rw_pep, rw_lv, rw_lj, rw_hv, rw_hj, out);

    z_kernel<<<8192, 256, 0, stream>>>(
        W_p1, b_p1, W_p2, b_p2,
        reinterpret_cast<float4*>(out + L_TOT * S_DIM));
}